// Round 1
// baseline (1375.069 us; speedup 1.0000x reference)
//
#include <hip/hip_runtime.h>
#include <cstdint>

typedef __attribute__((ext_vector_type(8))) __bf16 bf16x8;
typedef __attribute__((ext_vector_type(4))) float f32x4;
typedef unsigned short u16;

__device__ __forceinline__ u16 f2bf(float f) {
  union { float f; uint32_t u; } v; v.f = f;
  uint32_t r = v.u + 0x7fffu + ((v.u >> 16) & 1u);
  return (u16)(r >> 16);
}
__device__ __forceinline__ float bf2f(u16 u) {
  union { uint32_t u; float f; } v; v.u = ((uint32_t)u) << 16;
  return v.f;
}

#define BM 128
#define BN 128
#define BK 64

// C[m][n] = sum_k A[m][k] * B[n][k]   (A: MxK row-major, B: NcxK row-major = B^T form)
// epilogue: out = acc*scale + bias[col]; out dtype bf16 or f32.
__global__ __launch_bounds__(256) void gemm_bt(
    const u16* __restrict__ A, const u16* __restrict__ B,
    const float* __restrict__ bias, void* __restrict__ Cout,
    int M, int Nc, int K,
    int64_t strideA, int64_t strideB, int64_t strideC,
    float scale, int c_is_bf16)
{
  __shared__ __align__(16) u16 As[BM * BK];
  __shared__ __align__(16) u16 Bs[BN * BK];

  const int tid  = threadIdx.x;
  const int wave = tid >> 6;
  const int lane = tid & 63;
  const int bz   = blockIdx.z;
  const int tileM = blockIdx.y * BM;
  const int tileN = blockIdx.x * BN;

  const u16* Ab = A + (int64_t)bz * strideA;
  const u16* Bb = B + (int64_t)bz * strideB;

  // staging: chunk = 8 bf16 (16B). chunk id = i*256 + tid -> row=chunk/8, col=(chunk%8)*8
  const int srow = tid >> 3;        // 0..31
  const int scol = (tid & 7) * 8;   // 0..56

  f32x4 zero = {0.f, 0.f, 0.f, 0.f};
  f32x4 acc[4][4];
#pragma unroll
  for (int i = 0; i < 4; ++i)
#pragma unroll
    for (int j = 0; j < 4; ++j)
      acc[i][j] = zero;

  const int wm = (wave >> 1) * 64;   // wave's M offset in tile
  const int wn = (wave & 1) * 64;    // wave's N offset in tile
  const int fr = lane & 15;          // fragment row (m or n)
  const int fq = (lane >> 4) * 8;    // fragment k sub-offset

  for (int k0 = 0; k0 < K; k0 += BK) {
#pragma unroll
    for (int i = 0; i < 4; ++i) {
      const u16* ga = Ab + (int64_t)(tileM + i * 32 + srow) * K + (k0 + scol);
      const u16* gb = Bb + (int64_t)(tileN + i * 32 + srow) * K + (k0 + scol);
      u16* la = As + (i * 256 + wave * 64) * 8;   // wave-uniform LDS base
      u16* lb = Bs + (i * 256 + wave * 64) * 8;
      __builtin_amdgcn_global_load_lds((__attribute__((address_space(1))) void*)(ga),
                                       (__attribute__((address_space(3))) void*)(la), 16, 0, 0);
      __builtin_amdgcn_global_load_lds((__attribute__((address_space(1))) void*)(gb),
                                       (__attribute__((address_space(3))) void*)(lb), 16, 0, 0);
    }
    __syncthreads();
#pragma unroll
    for (int kk = 0; kk < BK; kk += 32) {
      bf16x8 af[4], bfr[4];
#pragma unroll
      for (int i = 0; i < 4; ++i)
        af[i] = *(const bf16x8*)&As[(wm + i * 16 + fr) * BK + kk + fq];
#pragma unroll
      for (int j = 0; j < 4; ++j)
        bfr[j] = *(const bf16x8*)&Bs[(wn + j * 16 + fr) * BK + kk + fq];
#pragma unroll
      for (int i = 0; i < 4; ++i)
#pragma unroll
        for (int j = 0; j < 4; ++j)
          acc[i][j] = __builtin_amdgcn_mfma_f32_16x16x32_bf16(af[i], bfr[j], acc[i][j], 0, 0, 0);
    }
    __syncthreads();
  }

  // C/D layout: col = lane&15, row = (lane>>4)*4 + r   [m89-verified]
  if (c_is_bf16) {
    u16* C = (u16*)Cout + (int64_t)bz * strideC;
#pragma unroll
    for (int i = 0; i < 4; ++i) {
#pragma unroll
      for (int j = 0; j < 4; ++j) {
        const int col = tileN + wn + j * 16 + (lane & 15);
        const float bsv = bias ? bias[col] : 0.f;
#pragma unroll
        for (int r = 0; r < 4; ++r) {
          const int row = tileM + wm + i * 16 + (lane >> 4) * 4 + r;
          C[(int64_t)row * Nc + col] = f2bf(acc[i][j][r] * scale + bsv);
        }
      }
    }
  } else {
    float* C = (float*)Cout + (int64_t)bz * strideC;
#pragma unroll
    for (int i = 0; i < 4; ++i) {
#pragma unroll
      for (int j = 0; j < 4; ++j) {
        const int col = tileN + wn + j * 16 + (lane & 15);
        const float bsv = bias ? bias[col] : 0.f;
#pragma unroll
        for (int r = 0; r < 4; ++r) {
          const int row = tileM + wm + i * 16 + (lane >> 4) * 4 + r;
          C[(int64_t)row * Nc + col] = acc[i][j][r] * scale + bsv;
        }
      }
    }
  }
}

__global__ __launch_bounds__(256) void cast_bf16(const float4* __restrict__ src,
                                                 ushort4* __restrict__ dst, int n4) {
  int i = blockIdx.x * blockDim.x + threadIdx.x;
  if (i >= n4) return;
  float4 f = src[i];
  ushort4 o;
  o.x = f2bf(f.x); o.y = f2bf(f.y); o.z = f2bf(f.z); o.w = f2bf(f.w);
  dst[i] = o;
}

// Column softmax (over s) of 512x512 score matrices, times V elementwise,
// written bf16 to out_pre[n, s, h*512 + t]  (the transpose(0,2,1,3).reshape layout).
__global__ __launch_bounds__(256) void softmax_mul(
    const float* __restrict__ Sc, const u16* __restrict__ V,
    u16* __restrict__ Y)
{
  const int b = blockIdx.y;       // n*H + h
  const int n = b >> 3;
  const int h = b & 7;
  const int sub = threadIdx.x >> 6;   // == wave id; owns a 128-row slice
  const int tl  = threadIdx.x & 63;
  const int t = blockIdx.x * 64 + tl; // column
  const float* S = Sc + (int64_t)b * 262144;
  const u16*  Vb = V  + (int64_t)b * 262144;

  // pass 1: per-thread online (max, sum) over its 128 rows of column t
  float m = -3.0e38f, l = 0.f;
  const int s0 = sub * 128;
  for (int s = s0; s < s0 + 128; ++s) {
    float x = S[s * 512 + t];
    float mn = fmaxf(m, x);
    l = l * __expf(m - mn) + __expf(x - mn);
    m = mn;
  }
  __shared__ float sm[4][64];
  __shared__ float sl[4][64];
  sm[sub][tl] = m; sl[sub][tl] = l;
  __syncthreads();
  float M4 = fmaxf(fmaxf(sm[0][tl], sm[1][tl]), fmaxf(sm[2][tl], sm[3][tl]));
  float L4 = sl[0][tl] * __expf(sm[0][tl] - M4) + sl[1][tl] * __expf(sm[1][tl] - M4)
           + sl[2][tl] * __expf(sm[2][tl] - M4) + sl[3][tl] * __expf(sm[3][tl] - M4);
  float inv = 1.f / L4;

  // pass 2: attn * V, scatter to out_pre[n, s, h*512 + t]
  u16* outp = Y + (int64_t)n * (512 * 4096) + h * 512 + t;
  for (int s = s0; s < s0 + 128; ++s) {
    float x = S[s * 512 + t];
    float y = __expf(x - M4) * inv;
    float vv = bf2f(Vb[s * 512 + t]);
    outp[(int64_t)s * 4096] = f2bf(y * vv);
  }
}

extern "C" void kernel_launch(void* const* d_in, const int* in_sizes, int n_in,
                              void* d_out, int out_size, void* d_ws, size_t ws_size,
                              hipStream_t stream) {
  const int64_t E = 16777216;  // 8*512*4096 == 4096*4096, element count of every matrix here
  const float* query = (const float*)d_in[0];
  const float* key   = (const float*)d_in[1];
  const float* value = (const float*)d_in[2];
  const float* Wq = (const float*)d_in[3];
  const float* bq = (const float*)d_in[4];
  const float* Wk = (const float*)d_in[5];
  const float* bk = (const float*)d_in[6];
  const float* Wv = (const float*)d_in[7];
  const float* bv = (const float*)d_in[8];
  const float* Wo = (const float*)d_in[9];
  const float* bo = (const float*)d_in[10];

  // workspace layout: 10 bf16 matrices of E elements = 335.5 MB total
  u16* qb = (u16*)d_ws;
  u16* kb = qb + E;
  u16* vb = kb + E;
  u16* wq = vb + E;
  u16* wk = wq + E;
  u16* wv = wk + E;
  u16* wo = wv + E;
  u16* Qp = wo + E;
  u16* Kp = Qp + E;
  u16* Vp = Kp + E;
  // aliases: after the QKV GEMMs, the bf16 input copies are dead.
  float* sc = (float*)qb;  // scores  (4E bytes == qb+kb regions)
  u16*   yp = vb;          // out_pre (2E bytes == vb region)

  const int n4 = (int)(E / 4);
  dim3 cb(256), cg((n4 + 255) / 256);
  cast_bf16<<<cg, cb, 0, stream>>>((const float4*)query, (ushort4*)qb, n4);
  cast_bf16<<<cg, cb, 0, stream>>>((const float4*)key,   (ushort4*)kb, n4);
  cast_bf16<<<cg, cb, 0, stream>>>((const float4*)value, (ushort4*)vb, n4);
  cast_bf16<<<cg, cb, 0, stream>>>((const float4*)Wq, (ushort4*)wq, n4);
  cast_bf16<<<cg, cb, 0, stream>>>((const float4*)Wk, (ushort4*)wk, n4);
  cast_bf16<<<cg, cb, 0, stream>>>((const float4*)Wv, (ushort4*)wv, n4);
  cast_bf16<<<cg, cb, 0, stream>>>((const float4*)Wo, (ushort4*)wo, n4);

  dim3 gb(256);
  dim3 gg(32, 32, 1);
  // Q/K/V projections: x @ W^T + b, output bf16
  gemm_bt<<<gg, gb, 0, stream>>>(qb, wq, bq, (void*)Qp, 4096, 4096, 4096, 0, 0, 0, 1.f, 1);
  gemm_bt<<<gg, gb, 0, stream>>>(kb, wk, bk, (void*)Kp, 4096, 4096, 4096, 0, 0, 0, 1.f, 1);
  gemm_bt<<<gg, gb, 0, stream>>>(vb, wv, bv, (void*)Vp, 4096, 4096, 4096, 0, 0, 0, 1.f, 1);

  // scores[b] = Q_b @ K_b^T / sqrt(512), fp32 output, 64 batches of 512^3
  dim3 sg(4, 4, 64);
  gemm_bt<<<sg, gb, 0, stream>>>(Qp, Kp, nullptr, (void*)sc, 512, 512, 512,
                                 262144, 262144, 262144, 0.04419417382415922f, 0);

  // column softmax + elementwise * V, write bf16 out_pre
  dim3 mg(8, 64);
  softmax_mul<<<mg, gb, 0, stream>>>(sc, Vp, yp);

  // out = out_pre @ Wo^T + bo, fp32 output
  gemm_bt<<<gg, gb, 0, stream>>>(yp, wo, bo, d_out, 4096, 4096, 4096, 0, 0, 0, 1.f, 0);
}

// Round 2
// 1300.127 us; speedup vs baseline: 1.0576x; 1.0576x over previous
//
#include <hip/hip_runtime.h>
#include <cstdint>

typedef __attribute__((ext_vector_type(8))) __bf16 bf16x8;
typedef __attribute__((ext_vector_type(4))) float f32x4;
typedef unsigned short u16;

__device__ __forceinline__ u16 f2bf(float f) {
  union { float f; uint32_t u; } v; v.f = f;
  uint32_t r = v.u + 0x7fffu + ((v.u >> 16) & 1u);
  return (u16)(r >> 16);
}
__device__ __forceinline__ float bf2f(u16 u) {
  union { uint32_t u; float f; } v; v.u = ((uint32_t)u) << 16;
  return v.f;
}

#define BM 128
#define BN 128
#define BK 64

// C[m][n] = sum_k A[m][k] * B[n][k]   (A: MxK row-major, B: NcxK row-major = B^T form)
// epilogue: out = acc*scale + bias[col]; out dtype bf16 or f32.
// LDS tiles are XOR-swizzled: logical (row, colblock c of 8 bf16) lives at
// physical chunk row*8 + (c ^ (row&7)) — kills the 16-way bank conflicts of
// the naive stride-128B layout while keeping global_load_lds's contiguous
// lane->LDS mapping legal (we permute the *source* addresses instead).
__global__ __launch_bounds__(256) void gemm_bt(
    const u16* __restrict__ A, const u16* __restrict__ B,
    const float* __restrict__ bias, void* __restrict__ Cout,
    int M, int Nc, int K,
    int64_t strideA, int64_t strideB, int64_t strideC,
    float scale, int c_is_bf16)
{
  __shared__ __align__(16) u16 As[BM * BK];
  __shared__ __align__(16) u16 Bs[BN * BK];

  const int tid  = threadIdx.x;
  const int wave = tid >> 6;
  const int lane = tid & 63;
  const int bz   = blockIdx.z;
  const int tileM = blockIdx.y * BM;
  const int tileN = blockIdx.x * BN;

  const u16* Ab = A + (int64_t)bz * strideA;
  const u16* Bb = B + (int64_t)bz * strideB;

  // staging: physical chunk p = i*256 + tid; logical row = p/8,
  // logical colblock = (p%8) ^ (row&7)  -> source col = that * 8
  const int srow = tid >> 3;                          // 0..31
  const int scl  = ((tid & 7) ^ (srow & 7)) * 8;      // swizzled source col

  f32x4 zero = {0.f, 0.f, 0.f, 0.f};
  f32x4 acc[4][4];
#pragma unroll
  for (int i = 0; i < 4; ++i)
#pragma unroll
    for (int j = 0; j < 4; ++j)
      acc[i][j] = zero;

  const int wm = (wave >> 1) * 64;   // wave's M offset in tile
  const int wn = (wave & 1) * 64;    // wave's N offset in tile
  const int fr = lane & 15;          // fragment row (m or n)
  const int cbase = (lane >> 4);     // k sub-block 0..3 (fq = cbase*8)
  const int sw = fr & 7;             // read-side swizzle key

  for (int k0 = 0; k0 < K; k0 += BK) {
#pragma unroll
    for (int i = 0; i < 4; ++i) {
      const u16* ga = Ab + (int64_t)(tileM + i * 32 + srow) * K + (k0 + scl);
      const u16* gb = Bb + (int64_t)(tileN + i * 32 + srow) * K + (k0 + scl);
      u16* la = As + (i * 256 + wave * 64) * 8;   // wave-uniform LDS base
      u16* lb = Bs + (i * 256 + wave * 64) * 8;
      __builtin_amdgcn_global_load_lds((__attribute__((address_space(1))) void*)(ga),
                                       (__attribute__((address_space(3))) void*)(la), 16, 0, 0);
      __builtin_amdgcn_global_load_lds((__attribute__((address_space(1))) void*)(gb),
                                       (__attribute__((address_space(3))) void*)(lb), 16, 0, 0);
    }
    __syncthreads();
#pragma unroll
    for (int kk = 0; kk < BK; kk += 32) {
      const int cb = (kk >> 3) + cbase;          // logical colblock 0..7
      const int sc8 = ((cb ^ sw) << 3);          // swizzled u16 offset in row
      bf16x8 af[4], bfr[4];
#pragma unroll
      for (int i = 0; i < 4; ++i)
        af[i] = *(const bf16x8*)&As[(wm + i * 16 + fr) * BK + sc8];
#pragma unroll
      for (int j = 0; j < 4; ++j)
        bfr[j] = *(const bf16x8*)&Bs[(wn + j * 16 + fr) * BK + sc8];
#pragma unroll
      for (int i = 0; i < 4; ++i)
#pragma unroll
        for (int j = 0; j < 4; ++j)
          acc[i][j] = __builtin_amdgcn_mfma_f32_16x16x32_bf16(af[i], bfr[j], acc[i][j], 0, 0, 0);
    }
    __syncthreads();
  }

  // C/D layout: col = lane&15, row = (lane>>4)*4 + r   [m89-verified]
  if (c_is_bf16) {
    u16* C = (u16*)Cout + (int64_t)bz * strideC;
#pragma unroll
    for (int i = 0; i < 4; ++i) {
#pragma unroll
      for (int j = 0; j < 4; ++j) {
        const int col = tileN + wn + j * 16 + (lane & 15);
        const float bsv = bias ? bias[col] : 0.f;
#pragma unroll
        for (int r = 0; r < 4; ++r) {
          const int row = tileM + wm + i * 16 + (lane >> 4) * 4 + r;
          C[(int64_t)row * Nc + col] = f2bf(acc[i][j][r] * scale + bsv);
        }
      }
    }
  } else {
    float* C = (float*)Cout + (int64_t)bz * strideC;
#pragma unroll
    for (int i = 0; i < 4; ++i) {
#pragma unroll
      for (int j = 0; j < 4; ++j) {
        const int col = tileN + wn + j * 16 + (lane & 15);
        const float bsv = bias ? bias[col] : 0.f;
#pragma unroll
        for (int r = 0; r < 4; ++r) {
          const int row = tileM + wm + i * 16 + (lane >> 4) * 4 + r;
          C[(int64_t)row * Nc + col] = acc[i][j][r] * scale + bsv;
        }
      }
    }
  }
}

__global__ __launch_bounds__(256) void cast_bf16(const float4* __restrict__ src,
                                                 ushort4* __restrict__ dst, int n4) {
  int i = blockIdx.x * blockDim.x + threadIdx.x;
  if (i >= n4) return;
  float4 f = src[i];
  ushort4 o;
  o.x = f2bf(f.x); o.y = f2bf(f.y); o.z = f2bf(f.z); o.w = f2bf(f.w);
  dst[i] = o;
}

// Column softmax (over s) of 512x512 score matrices, times V elementwise,
// written bf16 to out_pre[n, s, h*512 + t]  (the transpose(0,2,1,3).reshape layout).
__global__ __launch_bounds__(256) void softmax_mul(
    const float* __restrict__ Sc, const u16* __restrict__ V,
    u16* __restrict__ Y)
{
  const int b = blockIdx.y;       // n*H + h
  const int n = b >> 3;
  const int h = b & 7;
  const int sub = threadIdx.x >> 6;   // == wave id; owns a 128-row slice
  const int tl  = threadIdx.x & 63;
  const int t = blockIdx.x * 64 + tl; // column
  const float* S = Sc + (int64_t)b * 262144;
  const u16*  Vb = V  + (int64_t)b * 262144;

  // pass 1: per-thread online (max, sum) over its 128 rows of column t
  float m = -3.0e38f, l = 0.f;
  const int s0 = sub * 128;
  for (int s = s0; s < s0 + 128; ++s) {
    float x = S[s * 512 + t];
    float mn = fmaxf(m, x);
    l = l * __expf(m - mn) + __expf(x - mn);
    m = mn;
  }
  __shared__ float sm[4][64];
  __shared__ float sl[4][64];
  sm[sub][tl] = m; sl[sub][tl] = l;
  __syncthreads();
  float M4 = fmaxf(fmaxf(sm[0][tl], sm[1][tl]), fmaxf(sm[2][tl], sm[3][tl]));
  float L4 = sl[0][tl] * __expf(sm[0][tl] - M4) + sl[1][tl] * __expf(sm[1][tl] - M4)
           + sl[2][tl] * __expf(sm[2][tl] - M4) + sl[3][tl] * __expf(sm[3][tl] - M4);
  float inv = 1.f / L4;

  // pass 2: attn * V, scatter to out_pre[n, s, h*512 + t]
  u16* outp = Y + (int64_t)n * (512 * 4096) + h * 512 + t;
  for (int s = s0; s < s0 + 128; ++s) {
    float x = S[s * 512 + t];
    float y = __expf(x - M4) * inv;
    float vv = bf2f(Vb[s * 512 + t]);
    outp[(int64_t)s * 4096] = f2bf(y * vv);
  }
}

extern "C" void kernel_launch(void* const* d_in, const int* in_sizes, int n_in,
                              void* d_out, int out_size, void* d_ws, size_t ws_size,
                              hipStream_t stream) {
  const int64_t E = 16777216;  // 8*512*4096 == 4096*4096, element count of every matrix here
  const float* query = (const float*)d_in[0];
  const float* key   = (const float*)d_in[1];
  const float* value = (const float*)d_in[2];
  const float* Wq = (const float*)d_in[3];
  const float* bq = (const float*)d_in[4];
  const float* Wk = (const float*)d_in[5];
  const float* bk = (const float*)d_in[6];
  const float* Wv = (const float*)d_in[7];
  const float* bv = (const float*)d_in[8];
  const float* Wo = (const float*)d_in[9];
  const float* bo = (const float*)d_in[10];

  // workspace layout: 10 bf16 matrices of E elements = 335.5 MB total
  u16* qb = (u16*)d_ws;
  u16* kb = qb + E;
  u16* vb = kb + E;
  u16* wq = vb + E;
  u16* wk = wq + E;
  u16* wv = wk + E;
  u16* wo = wv + E;
  u16* Qp = wo + E;
  u16* Kp = Qp + E;
  u16* Vp = Kp + E;
  // aliases: after the QKV GEMMs, the bf16 input copies are dead.
  float* sc = (float*)qb;  // scores  (4E bytes == qb+kb regions)
  u16*   yp = vb;          // out_pre (2E bytes == vb region)

  const int n4 = (int)(E / 4);
  dim3 cb(256), cg((n4 + 255) / 256);
  cast_bf16<<<cg, cb, 0, stream>>>((const float4*)query, (ushort4*)qb, n4);
  cast_bf16<<<cg, cb, 0, stream>>>((const float4*)key,   (ushort4*)kb, n4);
  cast_bf16<<<cg, cb, 0, stream>>>((const float4*)value, (ushort4*)vb, n4);
  cast_bf16<<<cg, cb, 0, stream>>>((const float4*)Wq, (ushort4*)wq, n4);
  cast_bf16<<<cg, cb, 0, stream>>>((const float4*)Wk, (ushort4*)wk, n4);
  cast_bf16<<<cg, cb, 0, stream>>>((const float4*)Wv, (ushort4*)wv, n4);
  cast_bf16<<<cg, cb, 0, stream>>>((const float4*)Wo, (ushort4*)wo, n4);

  dim3 gb(256);
  dim3 gg(32, 32, 1);
  // Q/K/V projections: x @ W^T + b, output bf16
  gemm_bt<<<gg, gb, 0, stream>>>(qb, wq, bq, (void*)Qp, 4096, 4096, 4096, 0, 0, 0, 1.f, 1);
  gemm_bt<<<gg, gb, 0, stream>>>(kb, wk, bk, (void*)Kp, 4096, 4096, 4096, 0, 0, 0, 1.f, 1);
  gemm_bt<<<gg, gb, 0, stream>>>(vb, wv, bv, (void*)Vp, 4096, 4096, 4096, 0, 0, 0, 1.f, 1);

  // scores[b] = Q_b @ K_b^T / sqrt(512), fp32 output, 64 batches of 512^3
  dim3 sg(4, 4, 64);
  gemm_bt<<<sg, gb, 0, stream>>>(Qp, Kp, nullptr, (void*)sc, 512, 512, 512,
                                 262144, 262144, 262144, 0.04419417382415922f, 0);

  // column softmax + elementwise * V, write bf16 out_pre
  dim3 mg(8, 64);
  softmax_mul<<<mg, gb, 0, stream>>>(sc, Vp, yp);

  // out = out_pre @ Wo^T + bo, fp32 output
  gemm_bt<<<gg, gb, 0, stream>>>(yp, wo, bo, d_out, 4096, 4096, 4096, 0, 0, 0, 1.f, 0);
}